// Round 8
// baseline (145.994 us; speedup 1.0000x reference)
//
#include <hip/hip_runtime.h>
#include <stdint.h>

#define DM 1024
#define LS 2048
#define RMS_EPS 1.1920928955078125e-07f
#define S2 0.0029296875f   // BC_SCALE^2 = 3/1024, exact in fp32

typedef __attribute__((ext_vector_type(8))) short bf16x8;
typedef __attribute__((ext_vector_type(4))) float f32x4;

__device__ __forceinline__ unsigned short f2bf(float f) {
  uint32_t u = __builtin_bit_cast(uint32_t, f);
  u += 0x7FFFu + ((u >> 16) & 1u);   // round-to-nearest-even
  return (unsigned short)(u >> 16);
}
__device__ __forceinline__ float bf2f(unsigned short s) {
  uint32_t u = ((uint32_t)s) << 16;
  return __builtin_bit_cast(float, u);
}

// ---------------------------------------------------------------------------
// K0: pack B (64x1024) and C (64x1024) fp32 -> stacked bf16 [128][1024]
// ---------------------------------------------------------------------------
__global__ __launch_bounds__(256) void k0_prep(const float* __restrict__ B,
                                               const float* __restrict__ C,
                                               unsigned short* __restrict__ Bbf) {
  int i4 = blockIdx.x * 256 + threadIdx.x;          // 0..32767 float4s
  const float4* src = (i4 < 16384) ? (const float4*)B : (const float4*)C;
  float4 v = src[i4 & 16383];
  ushort4 o;
  o.x = f2bf(v.x); o.y = f2bf(v.y); o.z = f2bf(v.z); o.w = f2bf(v.w);
  ((ushort4*)Bbf)[i4] = o;
}

// ---------------------------------------------------------------------------
// KF: everything-after-k0 fused.  512 blocks (b:4 x t-tile:128, XCD-swizzled)
// x 256 thr (4 waves), 74.8 KB LDS -> 2 blocks/CU.
// S: stage u[1024][t0-16..t0+16) -> bf16 tile[128 k8][32] (v8-proven, XOR ^kq).
// G: free-run GEMM [B;C]@tile, af from L2-resident Bbf, unroll 8 (deeper
//    load pipeline than v8's 4).  Waves 2-3 skip halo cols (Cu unused there).
// Kw: acc -> BuCuB (bf16, SEPARATE buffer -- tile stays live for conv);
//    proven recurrence; written DIAGONALLY: Kwd[s][t] = Kw[t][t+16-s].
// Conv: per thread 4 consecutive d; for each staged col s: 1 ds_read_b64
//    (u bf16, conflict-spread by ^kq) + uniform-broadcast Kwd[s] row + fmaf
//    into y[4][16] regs; static t-ranges (no zero taps); skip term at s=16+t.
// RMS: shfl-xor over wave + 4x16 LDS + rsqv; normalize; 16B stores.
// ---------------------------------------------------------------------------
__global__ __launch_bounds__(256) void kf(const float* __restrict__ u,
                                          const unsigned short* __restrict__ Bbf,
                                          const float* __restrict__ A,
                                          const float* __restrict__ Dv,
                                          const float* __restrict__ nw,
                                          float* __restrict__ out) {
  const int wg = blockIdx.x;                    // 0..511
  const int sw = (wg & 7) * 64 + (wg >> 3);     // chunked XCD swizzle (bijective)
  const int b  = sw >> 7;
  const int t0 = (sw & 127) * 16;
  const int tid  = threadIdx.x;
  const int lane = tid & 63;
  const int w    = tid >> 6;                    // 0..3
  const int nn = lane & 15, q = lane >> 4;
  const float* ub = u + (size_t)b * DM * LS;

  __shared__ __align__(16) bf16x8 tile[128][32];        // 64 KB, lives S -> conv
  __shared__ __align__(16) unsigned short BuCuB[32][136]; // 8704 B (bf16 Bu/Cu)
  __shared__ __align__(16) float Kwd[32][16];           // 2 KB, diagonal Kw
  __shared__ float SSr[4][16];
  __shared__ float rsqv[16];

  // zero Kwd before barrier(1); Kw writes happen after barrier(2)
  ((float*)Kwd)[tid]       = 0.f;
  ((float*)Kwd)[tid + 256] = 0.f;

  { // ---- Phase S: one-shot stage (v8-proven). wave w: k in [256w,+256) ----
    const int kq = lane >> 3;                   // 0..7
    const int lo = lane & 7;                    // 0..7 col-quads
    const int gcol = t0 - 16 + 4*lo;
    #pragma unroll
    for (int hh = 0; hh < 4; ++hh) {
      const int krow = 256*w + 32*kq + 8*hh;
      float4 vv[8];
      if (gcol >= 0) {
        #pragma unroll
        for (int r = 0; r < 8; ++r)             // 128B row segments
          vv[r] = *(const float4*)(ub + (size_t)(krow + r) * LS + gcol);
      } else {
        #pragma unroll
        for (int r = 0; r < 8; ++r) vv[r] = make_float4(0.f, 0.f, 0.f, 0.f);
      }
      const int k8 = krow >> 3;                 // 32w + 4kq + hh
      #pragma unroll
      for (int c = 0; c < 4; ++c) {
        union { bf16x8 v; unsigned short s[8]; } t8;
        #pragma unroll
        for (int r = 0; r < 8; ++r) t8.s[r] = f2bf(((const float*)&vv[r])[c]);
        tile[k8][(4*lo + c) ^ kq] = t8.v;       // (k8>>2)&7 == kq
      }
    }
  }
  __syncthreads();                              // (1)

  // ---- Phase G: free-run GEMM (v8 structure, unroll 8) ----
  f32x4 acc[2][2] = {};                         // [rt(M16)][cn(N16)]
  const unsigned short* arow0 = Bbf + (size_t)(32*w + nn) * DM + 8*q;
  #pragma unroll 8
  for (int it = 0; it < 32; ++it) {
    const int sx = nn ^ (it & 7);               // read swizzle ((4it+q)>>2 = it)
    bf16x8 bf1 = tile[4*it + q][16 + sx];       // output cols
    bf16x8 af0 = *(const bf16x8*)(arow0 + 32*it);
    bf16x8 af1 = *(const bf16x8*)(arow0 + (size_t)16*DM + 32*it);
    acc[0][1] = __builtin_amdgcn_mfma_f32_16x16x32_bf16(af0, bf1, acc[0][1], 0, 0, 0);
    acc[1][1] = __builtin_amdgcn_mfma_f32_16x16x32_bf16(af1, bf1, acc[1][1], 0, 0, 0);
    if (w < 2) {                                // halo cols: Bu rows only
      bf16x8 bf0 = tile[4*it + q][sx];
      acc[0][0] = __builtin_amdgcn_mfma_f32_16x16x32_bf16(af0, bf0, acc[0][0], 0, 0, 0);
      acc[1][0] = __builtin_amdgcn_mfma_f32_16x16x32_bf16(af1, bf0, acc[1][0], 0, 0, 0);
    }
  }

  // ---- acc -> BuCuB (bf16).  Disjoint from tile: no barrier needed first.
  // C/D layout (proven): col = lane&15, row = 4*(lane>>4)+reg.
  #pragma unroll
  for (int rt = 0; rt < 2; ++rt)
    #pragma unroll
    for (int cn = 0; cn < 2; ++cn) {
      ushort4 pk;
      pk.x = f2bf(acc[rt][cn][0]); pk.y = f2bf(acc[rt][cn][1]);
      pk.z = f2bf(acc[rt][cn][2]); pk.w = f2bf(acc[rt][cn][3]);
      *(ushort4*)&BuCuB[16*cn + nn][32*w + 16*rt + 4*q] = pk;
    }
  __syncthreads();                              // (2)

  { // ---- Kw[t][j] = S2*sum_n Cu[t][n] A^j[n] Bu[t-j][n], diagonal store ----
    const int t = tid >> 4, p = tid & 15;
    const ushort4 cub = *(const ushort4*)&BuCuB[16 + t][64 + 4*p];
    const float4 aa = *(const float4*)(A + 4*p);
    float pw0 = bf2f(cub.x) * S2, pw1 = bf2f(cub.y) * S2;
    float pw2 = bf2f(cub.z) * S2, pw3 = bf2f(cub.w) * S2;
    #pragma unroll
    for (int j = 0; j < 16; ++j) {
      const ushort4 b4 = *(const ushort4*)&BuCuB[16 + t - j][4*p];
      float s = pw0*bf2f(b4.x) + pw1*bf2f(b4.y) + pw2*bf2f(b4.z) + pw3*bf2f(b4.w);
      s += __shfl_xor(s, 1, 64);
      s += __shfl_xor(s, 2, 64);
      s += __shfl_xor(s, 4, 64);
      s += __shfl_xor(s, 8, 64);
      if (p == 0) Kwd[t + 16 - j][t] = s;       // diagonal: col s needs row Kwd[s]
      pw0 *= aa.x; pw1 *= aa.y; pw2 *= aa.z; pw3 *= aa.w;
    }
  }
  __syncthreads();                              // (3)

  // ---- Conv + skip from LDS tile.  Thread: d = 4*tid .. 4*tid+3. ----
  const int k8c = tid >> 1, hf = tid & 1;
  const int kqc = (k8c >> 2) & 7;
  const int d0 = 4 * tid;
  float Dd[4];
  #pragma unroll
  for (int i = 0; i < 4; ++i) Dd[i] = Dv[d0 + i];
  float y[4][16];
  #pragma unroll
  for (int d = 0; d < 4; ++d)
    #pragma unroll
    for (int t = 0; t < 16; ++t) y[d][t] = 0.f;

  #pragma unroll
  for (int s = 1; s < 32; ++s) {
    const ushort4 uv = *(const ushort4*)((const char*)&tile[k8c][s ^ kqc] + 8*hf);
    const float f0 = bf2f(uv.x), f1 = bf2f(uv.y), f2 = bf2f(uv.z), f3 = bf2f(uv.w);
    const f32x4 kv0 = *(const f32x4*)&Kwd[s][0];   // uniform addr: broadcast
    const f32x4 kv1 = *(const f32x4*)&Kwd[s][4];
    const f32x4 kv2 = *(const f32x4*)&Kwd[s][8];
    const f32x4 kv3 = *(const f32x4*)&Kwd[s][12];
    const int tlo = (s >= 17) ? (s - 16) : 0;      // valid t: j = t+16-s in [0,15]
    const int thi = (s <= 16) ? (s - 1) : 15;
    #pragma unroll
    for (int t = 0; t < 16; ++t) {
      if (t < tlo || t > thi) continue;            // static under full unroll
      const float kvt = (t < 4) ? kv0[t] : (t < 8) ? kv1[t-4]
                       : (t < 12) ? kv2[t-8] : kv3[t-12];
      y[0][t] = fmaf(kvt, f0, y[0][t]);
      y[1][t] = fmaf(kvt, f1, y[1][t]);
      y[2][t] = fmaf(kvt, f2, y[2][t]);
      y[3][t] = fmaf(kvt, f3, y[3][t]);
    }
    if (s >= 16) {                                 // skip term u*D at t = s-16
      const int t = s - 16;
      y[0][t] = fmaf(Dd[0], f0, y[0][t]);
      y[1][t] = fmaf(Dd[1], f1, y[1][t]);
      y[2][t] = fmaf(Dd[2], f2, y[2][t]);
      y[3][t] = fmaf(Dd[3], f3, y[3][t]);
    }
  }

  // ---- RMS: ps[t] = sum_d y^2, wave shfl reduce, cross-wave via LDS ----
  float ps[16];
  #pragma unroll
  for (int t = 0; t < 16; ++t)
    ps[t] = fmaf(y[0][t], y[0][t], fmaf(y[1][t], y[1][t],
            fmaf(y[2][t], y[2][t], y[3][t]*y[3][t])));
  #pragma unroll
  for (int t = 0; t < 16; ++t) {
    ps[t] += __shfl_xor(ps[t], 1, 64);
    ps[t] += __shfl_xor(ps[t], 2, 64);
    ps[t] += __shfl_xor(ps[t], 4, 64);
    ps[t] += __shfl_xor(ps[t], 8, 64);
    ps[t] += __shfl_xor(ps[t], 16, 64);
    ps[t] += __shfl_xor(ps[t], 32, 64);
  }
  if (lane == 0) {
    *(float4*)&SSr[w][0]  = make_float4(ps[0],  ps[1],  ps[2],  ps[3]);
    *(float4*)&SSr[w][4]  = make_float4(ps[4],  ps[5],  ps[6],  ps[7]);
    *(float4*)&SSr[w][8]  = make_float4(ps[8],  ps[9],  ps[10], ps[11]);
    *(float4*)&SSr[w][12] = make_float4(ps[12], ps[13], ps[14], ps[15]);
  }
  __syncthreads();                              // (4)
  if (tid < 16) {
    float s = SSr[0][tid] + SSr[1][tid] + SSr[2][tid] + SSr[3][tid];
    rsqv[tid] = rsqrtf(s * (1.f/1024.f) + RMS_EPS);
  }
  __syncthreads();                              // (5)

  // ---- normalize + store: per d-row 4x16B contiguous ----
  const f32x4 rq0 = *(const f32x4*)&rsqv[0];
  const f32x4 rq1 = *(const f32x4*)&rsqv[4];
  const f32x4 rq2 = *(const f32x4*)&rsqv[8];
  const f32x4 rq3 = *(const f32x4*)&rsqv[12];
  float* ob = out + (size_t)b * DM * LS;
  #pragma unroll
  for (int d = 0; d < 4; ++d) {
    const float wn2 = nw[d0 + d];
    float* orow = ob + (size_t)(d0 + d) * LS + t0;
    float4 o;
    o.x = y[d][0]*rq0[0]*wn2;  o.y = y[d][1]*rq0[1]*wn2;
    o.z = y[d][2]*rq0[2]*wn2;  o.w = y[d][3]*rq0[3]*wn2;
    *(float4*)(orow + 0) = o;
    o.x = y[d][4]*rq1[0]*wn2;  o.y = y[d][5]*rq1[1]*wn2;
    o.z = y[d][6]*rq1[2]*wn2;  o.w = y[d][7]*rq1[3]*wn2;
    *(float4*)(orow + 4) = o;
    o.x = y[d][8]*rq2[0]*wn2;  o.y = y[d][9]*rq2[1]*wn2;
    o.z = y[d][10]*rq2[2]*wn2; o.w = y[d][11]*rq2[3]*wn2;
    *(float4*)(orow + 8) = o;
    o.x = y[d][12]*rq3[0]*wn2; o.y = y[d][13]*rq3[1]*wn2;
    o.z = y[d][14]*rq3[2]*wn2; o.w = y[d][15]*rq3[3]*wn2;
    *(float4*)(orow + 12) = o;
  }
}

// ---------------------------------------------------------------------------
extern "C" void kernel_launch(void* const* d_in, const int* in_sizes, int n_in,
                              void* d_out, int out_size, void* d_ws, size_t ws_size,
                              hipStream_t stream) {
  // inputs: [0]=L(int,1), [1]=u, [2]=A, [3]=B, [4]=C, [5]=D, [6]=norm_w
  const float* u  = (const float*)d_in[1];
  const float* A  = (const float*)d_in[2];
  const float* B  = (const float*)d_in[3];
  const float* C  = (const float*)d_in[4];
  const float* Dv = (const float*)d_in[5];
  const float* nw = (const float*)d_in[6];
  float* out = (float*)d_out;

  unsigned short* Bbf = (unsigned short*)d_ws;   // 256 KB

  k0_prep<<<dim3(128), dim3(256), 0, stream>>>(B, C, Bbf);
  kf     <<<dim3(512), dim3(256), 0, stream>>>(u, Bbf, A, Dv, nw, out);
}